// Round 1
// baseline (1512.528 us; speedup 1.0000x reference)
//
#include <hip/hip_runtime.h>

// GraphSAGE on MI355X.
// adj is 0.001-dense (avg degree ~16). One 1.07 GB scan of adj (the roofline).
// R9 (this round):
//  - k_count split into k_scan + k_fill. The old direct-slot scatter made the
//    slot store depend on the atomicAdd RETURN, issued after the prefetch
//    loads -> s_waitcnt vmcnt(0) drained the 4-deep pipeline on ~40% of wave
//    iterations. k_scan now writes hits to PRIVATE per-thread buffers (no
//    atomics, no data-dependent waits -> pure stream); k_fill (tiny) does the
//    atomic slot placement afterwards.
//  - k_layer: 16 nodes/block, 1024 blocks -> 4 blocks/CU (was 2) to halve the
//    latency exposure of the gather chains + Wt stream at low occupancy.

#define NN 16384          // nodes
#define SLOTC 64          // per-target slot capacity (deg~Pois(16.4); P(>64)~1e-19)
#define HCAP 8            // private hit-buffer capacity per scan thread
                          // (hits/thread ~ Pois(0.5); P(>8) ~ 1e-10, fallback is correct)

typedef int iv4 __attribute__((ext_vector_type(4)));   // native vector for ntload

// ---- workspace layout (bytes) ----
#define OFF_DEG   0u
#define OFF_SLOT  65536u                               // int[16384*64] = 4 MB
#define OFF_WT0   (65536u + 4194304u)                  // 4259840
#define OFF_WT1   (OFF_WT0 + 131072u)                  // Wt0 [256][128] f32
#define OFF_WT2   (OFF_WT1 + 131072u)                  // Wt1 [256][128] f32
#define OFF_H1    (OFF_WT2 + 65536u)                   // Wt2 [256][64] f32
#define OFF_H2    (OFF_H1 + 4u * NN * 128u)
#define OFF_HCNT  (OFF_H2 + 4u * NN * 128u)            // u8[524288] = 0.5 MB
#define OFF_HBUF  (OFF_HCNT + 524288u)                 // u32[524288*8] = 16 MB

// ---------- kernel 0: transpose [Wl;Wr] -> Wt[256][FOUT]; zero deg ----------
__global__ void k_wt(const float* __restrict__ Wl0, const float* __restrict__ Wr0,
                     const float* __restrict__ Wl1, const float* __restrict__ Wr1,
                     const float* __restrict__ Wl2, const float* __restrict__ Wr2,
                     float* __restrict__ wt0, float* __restrict__ wt1,
                     float* __restrict__ wt2, int* __restrict__ deg) {
    int g = blockIdx.x * 256 + threadIdx.x;
    if (g < NN) deg[g] = 0;            // runs before k_scan on the stream
    if (g < 32768) {
        int k = g >> 7, o = g & 127;
        wt0[g] = (k < 128) ? Wl0[o * 128 + k] : Wr0[o * 128 + (k - 128)];
    } else if (g < 65536) {
        int gg = g - 32768;
        int k = gg >> 7, o = gg & 127;
        wt1[gg] = (k < 128) ? Wl1[o * 128 + k] : Wr1[o * 128 + (k - 128)];
    } else if (g < 81920) {
        int gg = g - 65536;
        int k = gg >> 6, o = gg & 63;
        wt2[gg] = (k < 128) ? Wl2[o * 128 + k] : Wr2[o * 128 + (k - 128)];
    }
}

// ---------- kernel 1a: scan adj, buffer hits privately (NO atomics) ----------
__device__ __forceinline__ void scan_emit(iv4 v, int idx4, unsigned int hbase,
                                          int& cnt, unsigned int* __restrict__ hbuf,
                                          int* __restrict__ deg,
                                          int* __restrict__ slots) {
    if ((v.x | v.y | v.z | v.w) == 0) return;   // fp 0.0f is all-zero bits
    int fb = idx4 << 2;
    int s = fb >> 14;              // row (source)
    int t = fb & (NN - 1);         // col (target)
    int w[4] = {v.x, v.y, v.z, v.w};
    #pragma unroll
    for (int k = 0; k < 4; ++k) {
        if (w[k] != 0) {
            if (cnt < HCAP) {
                // plain store, nothing waits on it -> prefetch pipeline intact
                hbuf[hbase + (unsigned int)cnt] =
                    ((unsigned int)s << 14) | (unsigned int)(t + k);
            } else {
                // statistically-never fallback: direct atomic slot placement
                int pos = atomicAdd(&deg[t + k], 1);
                if (pos < SLOTC) slots[(t + k) * SLOTC + pos] = s;
            }
            ++cnt;
        }
    }
}

// 2-ahead prefetch, 4 loads in flight; the emit path now has NO vmcnt(0)
// drain (stores have no consumers), so the wave only ever waits vmcnt(2).
__global__ __launch_bounds__(256) void k_scan(
    const iv4* __restrict__ adj4, int* __restrict__ deg,
    int* __restrict__ slots, unsigned int* __restrict__ hbuf,
    unsigned char* __restrict__ hcnt) {
    const int stride = 2048 * 256;         // 2^19; total4 = 2^26 = 128 strides
    const int g0 = blockIdx.x * 256 + threadIdx.x;
    const unsigned int hbase = ((unsigned int)g0) << 3;   // HCAP = 8
    int cnt = 0;
    int i = g0;
    iv4 a = __builtin_nontemporal_load(&adj4[i]);
    iv4 b = __builtin_nontemporal_load(&adj4[i + stride]);
    #pragma unroll 1
    for (int n = 0; n < 63; ++n) {
        iv4 c = __builtin_nontemporal_load(&adj4[i + 2 * stride]);
        iv4 d = __builtin_nontemporal_load(&adj4[i + 3 * stride]);
        scan_emit(a, i, hbase, cnt, hbuf, deg, slots);
        scan_emit(b, i + stride, hbase, cnt, hbuf, deg, slots);
        a = c; b = d; i += 2 * stride;
    }
    scan_emit(a, i, hbase, cnt, hbuf, deg, slots);
    scan_emit(b, i + stride, hbase, cnt, hbuf, deg, slots);
    hcnt[g0] = (unsigned char)(cnt > HCAP ? HCAP : cnt);
}

// ---------- kernel 1b: scatter buffered hits into slot lists ----------
__global__ __launch_bounds__(256) void k_fill(
    const unsigned int* __restrict__ hbuf, const unsigned char* __restrict__ hcnt,
    int* __restrict__ deg, int* __restrict__ slots) {
    int g = blockIdx.x * 256 + threadIdx.x;
    int cnt = hcnt[g];
    unsigned int hbase = ((unsigned int)g) << 3;
    for (int j = 0; j < cnt; ++j) {
        unsigned int v = hbuf[hbase + (unsigned int)j];
        int s = (int)(v >> 14);
        int t = (int)(v & (NN - 1));
        int pos = atomicAdd(&deg[t], 1);
        if (pos < SLOTC) slots[t * SLOTC + pos] = s;
    }
}

// ---------- kernel 2: fused SAGE layer (mean-agg + Wt GEMM + bias (+ReLU)) ----
// 16 nodes/block, 1024 blocks -> 4 blocks/CU. Gather: 16 threads/node x
// 2 float4; int4 index load gives 4 edges -> 8 independent row loads in
// flight per cluster. GEMM: NPT=2 (FOUT=128) / 1 (FOUT=64).
// LDS z[16][66] float4: slots [0,32)=agg, [32,64)=self, 2 pad.
template <int FOUT, bool RELU>
__global__ __launch_bounds__(256) void k_layer(
    const float4* __restrict__ hin,    // [NN][32] float4
    float* __restrict__ hout,          // [NN][FOUT]
    const int* __restrict__ slots, const int* __restrict__ deg,
    const float4* __restrict__ Wt4,    // [256][FOUT/4]
    const float* __restrict__ bias)    // [FOUT]
{
    constexpr int S4 = 66;             // float4 stride per node row
    __shared__ float4 z[16 * S4];
    const int tid = threadIdx.x;
    const int nodeBase = blockIdx.x * 16;

    // stage self rows: 512 float4s, coalesced (32 consecutive tids = one row)
    #pragma unroll
    for (int r = 0; r < 2; ++r) {
        int g = tid + 256 * r;
        int n = g >> 5, j = g & 31;
        z[n * S4 + 32 + j] = hin[(nodeBase + n) * 32 + j];
    }

    // mean aggregation: 16-thread cluster per node, 2 float4s/thread
    {
        const int nl = tid >> 4;       // 0..15 node-local
        const int q = tid & 15;        // 0..15
        const int node = nodeBase + nl;
        const int d = deg[node];
        const int dc = d < SLOTC ? d : SLOTC;
        const int* el = slots + node * SLOTC;   // 256B-aligned
        float4 acc0 = make_float4(0.f, 0.f, 0.f, 0.f);
        float4 acc1 = make_float4(0.f, 0.f, 0.f, 0.f);
        int e = 0;
        for (; e + 4 <= dc; e += 4) {
            int4 s4 = *(const int4*)(el + e);
            const float4* r0 = hin + s4.x * 32;
            const float4* r1 = hin + s4.y * 32;
            const float4* r2 = hin + s4.z * 32;
            const float4* r3 = hin + s4.w * 32;
            float4 v0 = r0[q],      v1 = r1[q],      v2 = r2[q],      v3 = r3[q];
            float4 u0 = r0[q + 16], u1 = r1[q + 16], u2 = r2[q + 16], u3 = r3[q + 16];
            acc0.x += (v0.x + v1.x) + (v2.x + v3.x);
            acc0.y += (v0.y + v1.y) + (v2.y + v3.y);
            acc0.z += (v0.z + v1.z) + (v2.z + v3.z);
            acc0.w += (v0.w + v1.w) + (v2.w + v3.w);
            acc1.x += (u0.x + u1.x) + (u2.x + u3.x);
            acc1.y += (u0.y + u1.y) + (u2.y + u3.y);
            acc1.z += (u0.z + u1.z) + (u2.z + u3.z);
            acc1.w += (u0.w + u1.w) + (u2.w + u3.w);
        }
        for (; e < dc; ++e) {
            const float4* r0 = hin + el[e] * 32;
            float4 va = r0[q], ua = r0[q + 16];
            acc0.x += va.x; acc0.y += va.y; acc0.z += va.z; acc0.w += va.w;
            acc1.x += ua.x; acc1.y += ua.y; acc1.z += ua.z; acc1.w += ua.w;
        }
        const float di = d > 0 ? 1.0f / (float)d : 0.0f;
        acc0.x *= di; acc0.y *= di; acc0.z *= di; acc0.w *= di;
        acc1.x *= di; acc1.y *= di; acc1.z *= di; acc1.w *= di;
        z[nl * S4 + q] = acc0;
        z[nl * S4 + q + 16] = acc1;
    }
    __syncthreads();

    // GEMM: out[16 x FOUT] = [agg|self][16 x 256] @ Wt + b
    constexpr int TO = FOUT / 4;       // 32 or 16
    constexpr int TN = 256 / TO;       // 8 or 16
    constexpr int NPT = 16 / TN;       // 2 or 1
    const int to = tid % TO;
    const int tn = tid / TO;

    float4 acc[NPT];
    #pragma unroll
    for (int m = 0; m < NPT; ++m) acc[m] = make_float4(0.f, 0.f, 0.f, 0.f);

    #pragma unroll 2
    for (int k4 = 0; k4 < 64; ++k4) {
        // Wt rows 4k4..4k4+3 at float4-col `to`: contiguous across lanes
        float4 w0 = Wt4[(4 * k4 + 0) * TO + to];
        float4 w1 = Wt4[(4 * k4 + 1) * TO + to];
        float4 w2 = Wt4[(4 * k4 + 2) * TO + to];
        float4 w3 = Wt4[(4 * k4 + 3) * TO + to];
        #pragma unroll
        for (int m = 0; m < NPT; ++m) {
            float4 a = z[(tn * NPT + m) * S4 + k4];   // ks 4k4..4k4+3
            acc[m].x += a.x * w0.x + a.y * w1.x + a.z * w2.x + a.w * w3.x;
            acc[m].y += a.x * w0.y + a.y * w1.y + a.z * w2.y + a.w * w3.y;
            acc[m].z += a.x * w0.z + a.y * w1.z + a.z * w2.z + a.w * w3.z;
            acc[m].w += a.x * w0.w + a.y * w1.w + a.z * w2.w + a.w * w3.w;
        }
    }

    // epilogue: +bias, optional ReLU, coalesced float4 store
    const float4 bb = ((const float4*)bias)[to];
    #pragma unroll
    for (int m = 0; m < NPT; ++m) {
        float4 o;
        o.x = acc[m].x + bb.x; o.y = acc[m].y + bb.y;
        o.z = acc[m].z + bb.z; o.w = acc[m].w + bb.w;
        if (RELU) {
            o.x = fmaxf(o.x, 0.f); o.y = fmaxf(o.y, 0.f);
            o.z = fmaxf(o.z, 0.f); o.w = fmaxf(o.w, 0.f);
        }
        ((float4*)hout)[(nodeBase + tn * NPT + m) * TO + to] = o;
    }
}

extern "C" void kernel_launch(void* const* d_in, const int* in_sizes, int n_in,
                              void* d_out, int out_size, void* d_ws, size_t ws_size,
                              hipStream_t stream) {
    const float* x = (const float*)d_in[0];
    const iv4* adj4 = (const iv4*)d_in[1];
    const float* Wl0 = (const float*)d_in[2];
    const float* b0 = (const float*)d_in[3];
    const float* Wr0 = (const float*)d_in[4];
    const float* Wl1 = (const float*)d_in[5];
    const float* b1 = (const float*)d_in[6];
    const float* Wr1 = (const float*)d_in[7];
    const float* Wl2 = (const float*)d_in[8];
    const float* b2 = (const float*)d_in[9];
    const float* Wr2 = (const float*)d_in[10];

    char* ws = (char*)d_ws;
    int* deg = (int*)(ws + OFF_DEG);
    int* slots = (int*)(ws + OFF_SLOT);
    float* wt0 = (float*)(ws + OFF_WT0);
    float* wt1 = (float*)(ws + OFF_WT1);
    float* wt2 = (float*)(ws + OFF_WT2);
    float* h1 = (float*)(ws + OFF_H1);
    float* h2 = (float*)(ws + OFF_H2);
    unsigned char* hcnt = (unsigned char*)(ws + OFF_HCNT);
    unsigned int* hbuf = (unsigned int*)(ws + OFF_HBUF);

    // 0) transpose weights + zero deg (precedes k_scan on this stream)
    k_wt<<<320, 256, 0, stream>>>(Wl0, Wr0, Wl1, Wr1, Wl2, Wr2,
                                  wt0, wt1, wt2, deg);
    // 1a) scan adj (the 1.07 GB roofline read), buffer hits privately
    k_scan<<<2048, 256, 0, stream>>>(adj4, deg, slots, hbuf, hcnt);
    // 1b) scatter buffered hits into slot lists
    k_fill<<<2048, 256, 0, stream>>>(hbuf, hcnt, deg, slots);
    // 2) three fused SAGE layers
    k_layer<128, true><<<NN / 16, 256, 0, stream>>>(
        (const float4*)x, h1, slots, deg, (const float4*)wt0, b0);
    k_layer<128, true><<<NN / 16, 256, 0, stream>>>(
        (const float4*)h1, h2, slots, deg, (const float4*)wt1, b1);
    k_layer<64, false><<<NN / 16, 256, 0, stream>>>(
        (const float4*)h2, (float*)d_out, slots, deg, (const float4*)wt2, b2);
}

// Round 2
// 1452.992 us; speedup vs baseline: 1.0410x; 1.0410x over previous
//
#include <hip/hip_runtime.h>

// GraphSAGE on MI355X.
// adj is 0.001-dense (avg degree ~16). One 1.07 GB scan of adj (the roofline)
// scatters edges DIRECTLY into per-target slot lists (atomicAdd on deg returns
// the slot index). Then 3 fused layers: sparse mean-agg + fp32 dense GEMM.
// R2 session history: pre-transposed Wt (coalesced W streams); 32 nodes/block,
// NPT=4 (wave's 128KB Wt stream serves 8 nodes); direct-slot scatter;
// software-pipelined scan (2-ahead prefetch, 4 loads in flight).
// R9 POST-MORTEM: splitting scan/scatter + 16-node layers REGRESSED +100us ->
// reverted; at 32 waves/CU the scan's TLP already hides atomic-return stalls.
// R10 (this round): scan loads are PLAIN, not nontemporal. The 6.3 TB/s
// measured ceiling is for plain loads; nt-load BW on gfx950 is unverified and
// the scan is the only component big enough to hide the unexplained ~400us.
// adj is read once, so L2/L3 pollution from plain loads costs nothing.

#define NN 16384          // nodes
#define SLOTC 64          // per-target slot capacity (deg~Pois(16.4); P(>64)~1e-19)

typedef int iv4 __attribute__((ext_vector_type(4)));

// ---- workspace layout (bytes) ----
#define OFF_DEG   0u
#define OFF_SLOT  65536u                               // int[16384*64] = 4 MB
#define OFF_WT0   (65536u + 4194304u)                  // 4259840
#define OFF_WT1   (OFF_WT0 + 131072u)                  // Wt0 [256][128] f32
#define OFF_WT2   (OFF_WT1 + 131072u)                  // Wt1 [256][128] f32
#define OFF_H1    (OFF_WT2 + 65536u)                   // Wt2 [256][64] f32
#define OFF_H2    (OFF_H1 + 4u * NN * 128u)

// ---------- kernel 0: transpose [Wl;Wr] -> Wt[256][FOUT]; zero deg ----------
__global__ void k_wt(const float* __restrict__ Wl0, const float* __restrict__ Wr0,
                     const float* __restrict__ Wl1, const float* __restrict__ Wr1,
                     const float* __restrict__ Wl2, const float* __restrict__ Wr2,
                     float* __restrict__ wt0, float* __restrict__ wt1,
                     float* __restrict__ wt2, int* __restrict__ deg) {
    int g = blockIdx.x * 256 + threadIdx.x;
    if (g < NN) deg[g] = 0;            // runs before k_count on the stream
    if (g < 32768) {
        int k = g >> 7, o = g & 127;
        wt0[g] = (k < 128) ? Wl0[o * 128 + k] : Wr0[o * 128 + (k - 128)];
    } else if (g < 65536) {
        int gg = g - 32768;
        int k = gg >> 7, o = gg & 127;
        wt1[gg] = (k < 128) ? Wl1[o * 128 + k] : Wr1[o * 128 + (k - 128)];
    } else if (g < 81920) {
        int gg = g - 65536;
        int k = gg >> 6, o = gg & 63;
        wt2[gg] = (k < 128) ? Wl2[o * 128 + k] : Wr2[o * 128 + (k - 128)];
    }
}

// ---------- kernel 1: scan adj once, scatter edges into slot lists ----------
__device__ __forceinline__ void emit_hits(iv4 v, int idx4, int* __restrict__ deg,
                                          int* __restrict__ slots) {
    if ((v.x | v.y | v.z | v.w) == 0) return;   // fp 0.0f is all-zero bits
    int base = idx4 << 2;
    int s = base >> 14;            // row (source)
    int t = base & (NN - 1);       // col (target)
    int w[4] = {v.x, v.y, v.z, v.w};
    #pragma unroll
    for (int k = 0; k < 4; ++k) {
        if (w[k] != 0) {
            int pos = atomicAdd(&deg[t + k], 1);   // returns slot index
            if (pos < SLOTC) slots[(t + k) * SLOTC + pos] = s;
        }
    }
}

// 2-ahead prefetch, 4 loads in flight. Loads are PLAIN (R10): the nt flag's
// load BW is unverified on gfx950; plain coalesced loads are the pattern that
// measures 6.3 TB/s. Per-wave stalls in the emit path are hidden by 32
// waves/CU of TLP (proven by the R9 null result).
__global__ __launch_bounds__(256) void k_count(
    const iv4* __restrict__ adj4, int* __restrict__ deg,
    int* __restrict__ slots) {
    const int stride = 2048 * 256;         // 2^19; total4 = 2^26 = 128 strides
    int i = blockIdx.x * 256 + threadIdx.x;
    iv4 a = adj4[i];
    iv4 b = adj4[i + stride];
    #pragma unroll 1
    for (int n = 0; n < 63; ++n) {
        iv4 c = adj4[i + 2 * stride];
        iv4 d = adj4[i + 3 * stride];
        emit_hits(a, i, deg, slots);
        emit_hits(b, i + stride, deg, slots);
        a = c; b = d; i += 2 * stride;
    }
    emit_hits(a, i, deg, slots);
    emit_hits(b, i + stride, deg, slots);
}

// ---------- kernel 2: fused SAGE layer (mean-agg + Wt GEMM + bias (+ReLU)) ----
// 32 nodes/block, 512 blocks. Gather: 8 threads/node x 4 float4; int4 index
// load gives 4 edges -> 16 independent row loads in flight per cluster.
// GEMM: NPT=4 -> wave's 128KB Wt stream serves 8 nodes (W is L2-resident).
// LDS z[32][264] floats: float4 slots [0,32)=agg, [32,64)=self, 2 pad.
template <int FOUT, bool RELU>
__global__ __launch_bounds__(256) void k_layer(
    const float4* __restrict__ hin,    // [NN][32] float4
    float* __restrict__ hout,          // [NN][FOUT]
    const int* __restrict__ slots, const int* __restrict__ deg,
    const float4* __restrict__ Wt4,    // [256][FOUT/4]
    const float* __restrict__ bias)    // [FOUT]
{
    constexpr int S4 = 66;             // float4 stride per node row
    __shared__ float4 z[32 * S4];
    const int tid = threadIdx.x;
    const int nodeBase = blockIdx.x * 32;

    // stage self rows: 1024 float4s, coalesced (32 consecutive tids = one row)
    #pragma unroll
    for (int r = 0; r < 4; ++r) {
        int g = tid + 256 * r;
        int n = g >> 5, j = g & 31;
        z[n * S4 + 32 + j] = hin[(nodeBase + n) * 32 + j];
    }

    // mean aggregation: 8-thread cluster per node, 4 float4s/thread,
    // int4 index loads + 4-row unroll
    {
        const int nl = tid >> 3;       // 0..31 node-local
        const int q = tid & 7;         // 0..7
        const int node = nodeBase + nl;
        const int d = deg[node];
        const int dc = d < SLOTC ? d : SLOTC;
        const int* el = slots + node * SLOTC;   // 256B-aligned
        float4 acc[4];
        #pragma unroll
        for (int k = 0; k < 4; ++k) acc[k] = make_float4(0.f, 0.f, 0.f, 0.f);
        int e = 0;
        for (; e + 4 <= dc; e += 4) {
            int4 s4 = *(const int4*)(el + e);
            const float4* r0 = hin + s4.x * 32;
            const float4* r1 = hin + s4.y * 32;
            const float4* r2 = hin + s4.z * 32;
            const float4* r3 = hin + s4.w * 32;
            #pragma unroll
            for (int k = 0; k < 4; ++k) {
                float4 v0 = r0[q + 8 * k];
                float4 v1 = r1[q + 8 * k];
                float4 v2 = r2[q + 8 * k];
                float4 v3 = r3[q + 8 * k];
                acc[k].x += (v0.x + v1.x) + (v2.x + v3.x);
                acc[k].y += (v0.y + v1.y) + (v2.y + v3.y);
                acc[k].z += (v0.z + v1.z) + (v2.z + v3.z);
                acc[k].w += (v0.w + v1.w) + (v2.w + v3.w);
            }
        }
        for (; e < dc; ++e) {
            const float4* r0 = hin + el[e] * 32;
            #pragma unroll
            for (int k = 0; k < 4; ++k) {
                float4 va = r0[q + 8 * k];
                acc[k].x += va.x; acc[k].y += va.y;
                acc[k].z += va.z; acc[k].w += va.w;
            }
        }
        const float di = d > 0 ? 1.0f / (float)d : 0.0f;
        #pragma unroll
        for (int k = 0; k < 4; ++k) {
            acc[k].x *= di; acc[k].y *= di; acc[k].z *= di; acc[k].w *= di;
            z[nl * S4 + q + 8 * k] = acc[k];
        }
    }
    __syncthreads();

    // GEMM: out[32 x FOUT] = [agg|self][32 x 256] @ Wt + b
    constexpr int TO = FOUT / 4;       // 32 or 16
    constexpr int TN = 256 / TO;       // 8 or 16
    constexpr int NPT = 32 / TN;       // 4 or 2
    const int to = tid % TO;
    const int tn = tid / TO;

    float4 acc[NPT];
    #pragma unroll
    for (int m = 0; m < NPT; ++m) acc[m] = make_float4(0.f, 0.f, 0.f, 0.f);

    #pragma unroll 2
    for (int k4 = 0; k4 < 64; ++k4) {
        // Wt rows 4k4..4k4+3 at float4-col `to`: contiguous across lanes
        float4 w0 = Wt4[(4 * k4 + 0) * TO + to];
        float4 w1 = Wt4[(4 * k4 + 1) * TO + to];
        float4 w2 = Wt4[(4 * k4 + 2) * TO + to];
        float4 w3 = Wt4[(4 * k4 + 3) * TO + to];
        #pragma unroll
        for (int m = 0; m < NPT; ++m) {
            float4 a = z[(tn * NPT + m) * S4 + k4];   // ks 4k4..4k4+3
            acc[m].x += a.x * w0.x + a.y * w1.x + a.z * w2.x + a.w * w3.x;
            acc[m].y += a.x * w0.y + a.y * w1.y + a.z * w2.y + a.w * w3.y;
            acc[m].z += a.x * w0.z + a.y * w1.z + a.z * w2.z + a.w * w3.z;
            acc[m].w += a.x * w0.w + a.y * w1.w + a.z * w2.w + a.w * w3.w;
        }
    }

    // epilogue: +bias, optional ReLU, coalesced float4 store
    const float4 bb = ((const float4*)bias)[to];
    #pragma unroll
    for (int m = 0; m < NPT; ++m) {
        float4 o;
        o.x = acc[m].x + bb.x; o.y = acc[m].y + bb.y;
        o.z = acc[m].z + bb.z; o.w = acc[m].w + bb.w;
        if (RELU) {
            o.x = fmaxf(o.x, 0.f); o.y = fmaxf(o.y, 0.f);
            o.z = fmaxf(o.z, 0.f); o.w = fmaxf(o.w, 0.f);
        }
        ((float4*)hout)[(nodeBase + tn * NPT + m) * TO + to] = o;
    }
}

extern "C" void kernel_launch(void* const* d_in, const int* in_sizes, int n_in,
                              void* d_out, int out_size, void* d_ws, size_t ws_size,
                              hipStream_t stream) {
    const float* x = (const float*)d_in[0];
    const iv4* adj4 = (const iv4*)d_in[1];
    const float* Wl0 = (const float*)d_in[2];
    const float* b0 = (const float*)d_in[3];
    const float* Wr0 = (const float*)d_in[4];
    const float* Wl1 = (const float*)d_in[5];
    const float* b1 = (const float*)d_in[6];
    const float* Wr1 = (const float*)d_in[7];
    const float* Wl2 = (const float*)d_in[8];
    const float* b2 = (const float*)d_in[9];
    const float* Wr2 = (const float*)d_in[10];

    char* ws = (char*)d_ws;
    int* deg = (int*)(ws + OFF_DEG);
    int* slots = (int*)(ws + OFF_SLOT);
    float* wt0 = (float*)(ws + OFF_WT0);
    float* wt1 = (float*)(ws + OFF_WT1);
    float* wt2 = (float*)(ws + OFF_WT2);
    float* h1 = (float*)(ws + OFF_H1);
    float* h2 = (float*)(ws + OFF_H2);

    // 0) transpose weights + zero deg (precedes k_count on this stream)
    k_wt<<<320, 256, 0, stream>>>(Wl0, Wr0, Wl1, Wr1, Wl2, Wr2,
                                  wt0, wt1, wt2, deg);
    // 1) scan adj (the 1.07 GB roofline read), scatter edges into slots
    k_count<<<2048, 256, 0, stream>>>(adj4, deg, slots);
    // 2) three fused SAGE layers
    k_layer<128, true><<<NN / 32, 256, 0, stream>>>(
        (const float4*)x, h1, slots, deg, (const float4*)wt0, b0);
    k_layer<128, true><<<NN / 32, 256, 0, stream>>>(
        (const float4*)h1, h2, slots, deg, (const float4*)wt1, b1);
    k_layer<64, false><<<NN / 32, 256, 0, stream>>>(
        (const float4*)h2, (float*)d_out, slots, deg, (const float4*)wt2, b2);
}

// Round 4
// 1410.302 us; speedup vs baseline: 1.0725x; 1.0303x over previous
//
#include <hip/hip_runtime.h>

// GraphSAGE on MI355X.
// adj is 0.001-dense (avg degree ~16). One 1.07 GB scan of adj (the roofline)
// scatters edges DIRECTLY into per-target slot lists (atomicAdd on deg returns
// the slot index). Then 3 fused layers: sparse mean-agg + fp32 dense GEMM.
// Proven structure (1412 us): pre-transposed Wt (coalesced W streams);
// 32 nodes/block, NPT=4 (wave's 128KB Wt stream serves 8 nodes); direct-slot
// scatter; software-pipelined scan (2-ahead prefetch, 4 loads in flight);
// NONTEMPORAL adj loads.
// R9 POST-MORTEM: splitting scan/scatter + 16-node layers REGRESSED +100us.
//   At 32 waves/CU the scan's TLP already hides the atomic-return stalls;
//   16-node layers doubled the Wt stream; k_fill added a 16MB round trip.
// R10 POST-MORTEM: plain (cached) adj loads REGRESSED +40us vs nontemporal.
//   Streaming 1.07 GB of adj through L2/L3 evicts the hot deg/slots lines the
//   scatter atomics live in; nt loads keep the scatter L2-resident. KEEP NT.
// R11: exact revert to the measured-best R0 configuration. (R3 bench attempt
//   of this source failed on container infra, not kernel — resubmitted as-is.)
//   Remaining dur_us is dominated by harness-fixed costs (4 GiB workspace
//   poison fill ~680us at 79% HBM peak + reset dispatch train); kernel-side
//   scan is at its 1.07 GB HBM roofline (~175us), layers ~40-60us each.

#define NN 16384          // nodes
#define SLOTC 64          // per-target slot capacity (deg~Pois(16.4); P(>64)~1e-19)

typedef int iv4 __attribute__((ext_vector_type(4)));   // native vector for ntload

// ---- workspace layout (bytes) ----
#define OFF_DEG   0u
#define OFF_SLOT  65536u                               // int[16384*64] = 4 MB
#define OFF_WT0   (65536u + 4194304u)                  // 4259840
#define OFF_WT1   (OFF_WT0 + 131072u)                  // Wt0 [256][128] f32
#define OFF_WT2   (OFF_WT1 + 131072u)                  // Wt1 [256][128] f32
#define OFF_H1    (OFF_WT2 + 65536u)                   // Wt2 [256][64] f32
#define OFF_H2    (OFF_H1 + 4u * NN * 128u)

// ---------- kernel 0: transpose [Wl;Wr] -> Wt[256][FOUT]; zero deg ----------
__global__ void k_wt(const float* __restrict__ Wl0, const float* __restrict__ Wr0,
                     const float* __restrict__ Wl1, const float* __restrict__ Wr1,
                     const float* __restrict__ Wl2, const float* __restrict__ Wr2,
                     float* __restrict__ wt0, float* __restrict__ wt1,
                     float* __restrict__ wt2, int* __restrict__ deg) {
    int g = blockIdx.x * 256 + threadIdx.x;
    if (g < NN) deg[g] = 0;            // runs before k_count on the stream
    if (g < 32768) {
        int k = g >> 7, o = g & 127;
        wt0[g] = (k < 128) ? Wl0[o * 128 + k] : Wr0[o * 128 + (k - 128)];
    } else if (g < 65536) {
        int gg = g - 32768;
        int k = gg >> 7, o = gg & 127;
        wt1[gg] = (k < 128) ? Wl1[o * 128 + k] : Wr1[o * 128 + (k - 128)];
    } else if (g < 81920) {
        int gg = g - 65536;
        int k = gg >> 6, o = gg & 63;
        wt2[gg] = (k < 128) ? Wl2[o * 128 + k] : Wr2[o * 128 + (k - 128)];
    }
}

// ---------- kernel 1: scan adj once, scatter edges into slot lists ----------
__device__ __forceinline__ void emit_hits(iv4 v, int idx4, int* __restrict__ deg,
                                          int* __restrict__ slots) {
    if ((v.x | v.y | v.z | v.w) == 0) return;   // fp 0.0f is all-zero bits
    int base = idx4 << 2;
    int s = base >> 14;            // row (source)
    int t = base & (NN - 1);       // col (target)
    int w[4] = {v.x, v.y, v.z, v.w};
    #pragma unroll
    for (int k = 0; k < 4; ++k) {
        if (w[k] != 0) {
            int pos = atomicAdd(&deg[t + k], 1);   // returns slot index
            if (pos < SLOTC) slots[(t + k) * SLOTC + pos] = s;
        }
    }
}

// 2-ahead prefetch, 4 loads in flight across the branchy emit. Loads are
// NONTEMPORAL (R10 A/B: nt is 40us faster — keeps deg/slots L2-resident).
__global__ __launch_bounds__(256) void k_count(
    const iv4* __restrict__ adj4, int* __restrict__ deg,
    int* __restrict__ slots) {
    const int stride = 2048 * 256;         // 2^19; total4 = 2^26 = 128 strides
    int i = blockIdx.x * 256 + threadIdx.x;
    iv4 a = __builtin_nontemporal_load(&adj4[i]);
    iv4 b = __builtin_nontemporal_load(&adj4[i + stride]);
    #pragma unroll 1
    for (int n = 0; n < 63; ++n) {
        iv4 c = __builtin_nontemporal_load(&adj4[i + 2 * stride]);
        iv4 d = __builtin_nontemporal_load(&adj4[i + 3 * stride]);
        emit_hits(a, i, deg, slots);
        emit_hits(b, i + stride, deg, slots);
        a = c; b = d; i += 2 * stride;
    }
    emit_hits(a, i, deg, slots);
    emit_hits(b, i + stride, deg, slots);
}

// ---------- kernel 2: fused SAGE layer (mean-agg + Wt GEMM + bias (+ReLU)) ----
// 32 nodes/block, 512 blocks. Gather: 8 threads/node x 4 float4; int4 index
// load gives 4 edges -> 16 independent row loads in flight per cluster.
// GEMM: NPT=4 -> wave's 128KB Wt stream serves 8 nodes (W is L2-resident).
// LDS z[32][264] floats: float4 slots [0,32)=agg, [32,64)=self, 2 pad.
template <int FOUT, bool RELU>
__global__ __launch_bounds__(256) void k_layer(
    const float4* __restrict__ hin,    // [NN][32] float4
    float* __restrict__ hout,          // [NN][FOUT]
    const int* __restrict__ slots, const int* __restrict__ deg,
    const float4* __restrict__ Wt4,    // [256][FOUT/4]
    const float* __restrict__ bias)    // [FOUT]
{
    constexpr int S4 = 66;             // float4 stride per node row
    __shared__ float4 z[32 * S4];
    const int tid = threadIdx.x;
    const int nodeBase = blockIdx.x * 32;

    // stage self rows: 1024 float4s, coalesced (32 consecutive tids = one row)
    #pragma unroll
    for (int r = 0; r < 4; ++r) {
        int g = tid + 256 * r;
        int n = g >> 5, j = g & 31;
        z[n * S4 + 32 + j] = hin[(nodeBase + n) * 32 + j];
    }

    // mean aggregation: 8-thread cluster per node, 4 float4s/thread,
    // int4 index loads + 4-row unroll
    {
        const int nl = tid >> 3;       // 0..31 node-local
        const int q = tid & 7;         // 0..7
        const int node = nodeBase + nl;
        const int d = deg[node];
        const int dc = d < SLOTC ? d : SLOTC;
        const int* el = slots + node * SLOTC;   // 256B-aligned
        float4 acc[4];
        #pragma unroll
        for (int k = 0; k < 4; ++k) acc[k] = make_float4(0.f, 0.f, 0.f, 0.f);
        int e = 0;
        for (; e + 4 <= dc; e += 4) {
            int4 s4 = *(const int4*)(el + e);
            const float4* r0 = hin + s4.x * 32;
            const float4* r1 = hin + s4.y * 32;
            const float4* r2 = hin + s4.z * 32;
            const float4* r3 = hin + s4.w * 32;
            #pragma unroll
            for (int k = 0; k < 4; ++k) {
                float4 v0 = r0[q + 8 * k];
                float4 v1 = r1[q + 8 * k];
                float4 v2 = r2[q + 8 * k];
                float4 v3 = r3[q + 8 * k];
                acc[k].x += (v0.x + v1.x) + (v2.x + v3.x);
                acc[k].y += (v0.y + v1.y) + (v2.y + v3.y);
                acc[k].z += (v0.z + v1.z) + (v2.z + v3.z);
                acc[k].w += (v0.w + v1.w) + (v2.w + v3.w);
            }
        }
        for (; e < dc; ++e) {
            const float4* r0 = hin + el[e] * 32;
            #pragma unroll
            for (int k = 0; k < 4; ++k) {
                float4 va = r0[q + 8 * k];
                acc[k].x += va.x; acc[k].y += va.y;
                acc[k].z += va.z; acc[k].w += va.w;
            }
        }
        const float di = d > 0 ? 1.0f / (float)d : 0.0f;
        #pragma unroll
        for (int k = 0; k < 4; ++k) {
            acc[k].x *= di; acc[k].y *= di; acc[k].z *= di; acc[k].w *= di;
            z[nl * S4 + q + 8 * k] = acc[k];
        }
    }
    __syncthreads();

    // GEMM: out[32 x FOUT] = [agg|self][32 x 256] @ Wt + b
    constexpr int TO = FOUT / 4;       // 32 or 16
    constexpr int TN = 256 / TO;       // 8 or 16
    constexpr int NPT = 32 / TN;       // 4 or 2
    const int to = tid % TO;
    const int tn = tid / TO;

    float4 acc[NPT];
    #pragma unroll
    for (int m = 0; m < NPT; ++m) acc[m] = make_float4(0.f, 0.f, 0.f, 0.f);

    #pragma unroll 2
    for (int k4 = 0; k4 < 64; ++k4) {
        // Wt rows 4k4..4k4+3 at float4-col `to`: contiguous across lanes
        float4 w0 = Wt4[(4 * k4 + 0) * TO + to];
        float4 w1 = Wt4[(4 * k4 + 1) * TO + to];
        float4 w2 = Wt4[(4 * k4 + 2) * TO + to];
        float4 w3 = Wt4[(4 * k4 + 3) * TO + to];
        #pragma unroll
        for (int m = 0; m < NPT; ++m) {
            float4 a = z[(tn * NPT + m) * S4 + k4];   // ks 4k4..4k4+3
            acc[m].x += a.x * w0.x + a.y * w1.x + a.z * w2.x + a.w * w3.x;
            acc[m].y += a.x * w0.y + a.y * w1.y + a.z * w2.y + a.w * w3.y;
            acc[m].z += a.x * w0.z + a.y * w1.z + a.z * w2.z + a.w * w3.z;
            acc[m].w += a.x * w0.w + a.y * w1.w + a.z * w2.w + a.w * w3.w;
        }
    }

    // epilogue: +bias, optional ReLU, coalesced float4 store
    const float4 bb = ((const float4*)bias)[to];
    #pragma unroll
    for (int m = 0; m < NPT; ++m) {
        float4 o;
        o.x = acc[m].x + bb.x; o.y = acc[m].y + bb.y;
        o.z = acc[m].z + bb.z; o.w = acc[m].w + bb.w;
        if (RELU) {
            o.x = fmaxf(o.x, 0.f); o.y = fmaxf(o.y, 0.f);
            o.z = fmaxf(o.z, 0.f); o.w = fmaxf(o.w, 0.f);
        }
        ((float4*)hout)[(nodeBase + tn * NPT + m) * TO + to] = o;
    }
}

extern "C" void kernel_launch(void* const* d_in, const int* in_sizes, int n_in,
                              void* d_out, int out_size, void* d_ws, size_t ws_size,
                              hipStream_t stream) {
    const float* x = (const float*)d_in[0];
    const iv4* adj4 = (const iv4*)d_in[1];
    const float* Wl0 = (const float*)d_in[2];
    const float* b0 = (const float*)d_in[3];
    const float* Wr0 = (const float*)d_in[4];
    const float* Wl1 = (const float*)d_in[5];
    const float* b1 = (const float*)d_in[6];
    const float* Wr1 = (const float*)d_in[7];
    const float* Wl2 = (const float*)d_in[8];
    const float* b2 = (const float*)d_in[9];
    const float* Wr2 = (const float*)d_in[10];

    char* ws = (char*)d_ws;
    int* deg = (int*)(ws + OFF_DEG);
    int* slots = (int*)(ws + OFF_SLOT);
    float* wt0 = (float*)(ws + OFF_WT0);
    float* wt1 = (float*)(ws + OFF_WT1);
    float* wt2 = (float*)(ws + OFF_WT2);
    float* h1 = (float*)(ws + OFF_H1);
    float* h2 = (float*)(ws + OFF_H2);

    // 0) transpose weights + zero deg (precedes k_count on this stream)
    k_wt<<<320, 256, 0, stream>>>(Wl0, Wr0, Wl1, Wr1, Wl2, Wr2,
                                  wt0, wt1, wt2, deg);
    // 1) scan adj (the 1.07 GB roofline read), scatter edges into slots
    k_count<<<2048, 256, 0, stream>>>(adj4, deg, slots);
    // 2) three fused SAGE layers
    k_layer<128, true><<<NN / 32, 256, 0, stream>>>(
        (const float4*)x, h1, slots, deg, (const float4*)wt0, b0);
    k_layer<128, true><<<NN / 32, 256, 0, stream>>>(
        (const float4*)h1, h2, slots, deg, (const float4*)wt1, b1);
    k_layer<64, false><<<NN / 32, 256, 0, stream>>>(
        (const float4*)h2, (float*)d_out, slots, deg, (const float4*)wt2, b2);
}